// Round 18
// baseline (55.187 us; speedup 1.0000x reference)
//
#include <hip/hip_runtime.h>
#include <hip/hip_bf16.h>

typedef __attribute__((ext_vector_type(8))) short bf16x8;
typedef __attribute__((ext_vector_type(4))) float f32x4;

#define NBLK 256   // blocks; 512 threads (8 waves); 1 block/CU (88 KB LDS), 2 waves/SIMD

__device__ __forceinline__ unsigned short f2bf(float f) {
    unsigned u = __float_as_uint(f);
    return (unsigned short)((u + 0x7fffu + ((u >> 16) & 1u)) >> 16);
}

__device__ __forceinline__ bf16x8 pack8(float4 x, float4 y) {
    bf16x8 r;
    r[0] = (short)f2bf(x.x); r[1] = (short)f2bf(x.y);
    r[2] = (short)f2bf(x.z); r[3] = (short)f2bf(x.w);
    r[4] = (short)f2bf(y.x); r[5] = (short)f2bf(y.y);
    r[6] = (short)f2bf(y.z); r[7] = (short)f2bf(y.w);
    return r;
}

__device__ __forceinline__ float ftanh(float x) {
    float e = __expf(2.f * x);
    return 1.f - 2.f / (e + 1.f);
}

// PROBE ROUND 2: the R16 kernel (masked-fused + in-wave ballot sort, 24.1us)
// wrapped in a reps-loop (host passes reps=4) with bijective per-rep window
// rotation ((wv + r*683) mod nwin; 683 coprime to 2048 windows). Staging paid
// once -> dur ~= startup + reps*steady. Each rep rewrites identical values ->
// deterministic & correct. Purpose: (a) current kernel's counters have been
// invisible (below the 40us harness fills) since R15; (b) decompose
// startup vs steady for the CURRENT structure (R12's decomposition measured
// the old masked/unsorted kernel and is stale).
// Layout (verified R1-R5): A row=lane&15, k=(lane>>4)*8+j; B col=lane&15
// (edge), same k; D col=lane&15 (edge), row=(lane>>4)*4+r -> f32x4 store/nt.
__global__ __launch_bounds__(512, 2) void k_fused(
    const int* __restrict__ ij, const float* __restrict__ desc,
    const float* __restrict__ layer1, const float* __restrict__ lin_w,
    const float* __restrict__ lin_b, float* __restrict__ out, int E, int reps) {

    __shared__ __align__(16) short wsm[11 * 512 * 8];   // 88 KiB; m=10 is lin_w

    for (int idx = threadIdx.x; idx < 11 * 512; idx += 512) {
        const int m = idx >> 9;
        const int fl = idx & 511;
        const int fi = fl >> 6, l = fl & 63;
        const int nt = fi >> 1, kk = fi & 1;
        const float* src = (m < 10) ? (layer1 + m * 4096) : lin_w;
        const float* sp = src + (nt * 16 + (l & 15)) * 64 + kk * 32 + (l >> 4) * 8;
        float4 x = *(const float4*)sp;
        float4 y = *(const float4*)(sp + 4);
        *(bf16x8*)(&wsm[idx * 8]) = pack8(x, y);
    }

    const int lane = threadIdx.x & 63;
    const int col = lane & 15;
    const int g = lane >> 4;
    const int kb = g * 8;
    const bf16x8 zero8 = {0, 0, 0, 0, 0, 0, 0, 0};

    __syncthreads();

    // lin fragments resident in registers (m=10 staged frags)
    bf16x8 al[4][2];
    #pragma unroll
    for (int fi = 0; fi < 8; ++fi)
        al[fi >> 1][fi & 1] = *(const bf16x8*)(&wsm[((80 + fi) * 64 + lane) * 8]);

    const int wv = blockIdx.x * 8 + (threadIdx.x >> 6);   // 0..2047
    const int nwin = (E + 63) >> 6;

    #pragma unroll 1
    for (int r = 0; r < reps; ++r) {
        int gw = wv + r * 683;
        while (gw >= nwin) gw -= nwin;
        const int base = gw * 64;
        if (base >= E) continue;

        // ---- in-wave sort of the 64-edge window by type (stable ballot rank) ----
        const int e_own = min(base + lane, E - 1);
        const int ty_own = ij[e_own];
        int rank = 0, below = 0;
        #pragma unroll
        for (int t = 0; t < 10; ++t) {
            const unsigned long long m = __ballot(ty_own == t);
            if (ty_own == t) rank = below + (int)__popcll(m & ((1ull << lane) - 1ull));
            below += (int)__popcll(m);
        }
        const int e_sorted = __builtin_amdgcn_ds_permute(rank << 2, e_own);
        const int ty_sorted = __builtin_amdgcn_ds_permute(rank << 2, ty_own);

        // ---- 4 sorted 16-edge tiles ----
        #pragma unroll 1
        for (int tp = 0; tp < 4; ++tp) {
            const int pbase = tp * 16;
            const int e_t = __shfl(e_sorted, pbase + col);
            const int ty_t = __shfl(ty_sorted, pbase + col);
            const int ty_lo = __shfl(ty_sorted, pbase);
            const int ty_hi = __shfl(ty_sorted, pbase + 15);

            const float* dp = desc + (size_t)e_t * 64 + kb;
            const float4 x0 = *(const float4*)dp,        y0 = *(const float4*)(dp + 4);
            const float4 x1 = *(const float4*)(dp + 32), y1 = *(const float4*)(dp + 36);
            const bf16x8 b0 = pack8(x0, y0);
            const bf16x8 b1 = pack8(x1, y1);

            f32x4 zL[4], zW[4];
            #pragma unroll
            for (int nt = 0; nt < 4; ++nt) {
                f32x4 z = {0.f, 0.f, 0.f, 0.f};
                z = __builtin_amdgcn_mfma_f32_16x16x32_bf16(al[nt][0], b0, z, 0, 0, 0);
                zL[nt] = __builtin_amdgcn_mfma_f32_16x16x32_bf16(al[nt][1], b1, z, 0, 0, 0);
                zW[nt] = (f32x4){0.f, 0.f, 0.f, 0.f};
            }

            #pragma unroll 1
            for (int m = ty_lo; m <= ty_hi; ++m) {
                if (!__any(ty_t == m)) continue;
                const bf16x8 m0 = (ty_t == m) ? b0 : zero8;
                const bf16x8 m1 = (ty_t == m) ? b1 : zero8;
                #pragma unroll
                for (int nt = 0; nt < 4; ++nt) {
                    const bf16x8 f0 = *(const bf16x8*)(&wsm[((m * 8 + nt * 2 + 0) * 64 + lane) * 8]);
                    const bf16x8 f1 = *(const bf16x8*)(&wsm[((m * 8 + nt * 2 + 1) * 64 + lane) * 8]);
                    zW[nt] = __builtin_amdgcn_mfma_f32_16x16x32_bf16(f0, m0, zW[nt], 0, 0, 0);
                    zW[nt] = __builtin_amdgcn_mfma_f32_16x16x32_bf16(f1, m1, zW[nt], 0, 0, 0);
                }
            }

            float* op = out + (size_t)e_t * 64 + g * 4;
            #pragma unroll
            for (int nt = 0; nt < 4; ++nt) {
                const float4 bias = *(const float4*)(lin_b + nt * 16 + g * 4);
                f32x4 rr;
                rr[0] = ftanh(zW[nt][0]) + zL[nt][0] + bias.x;
                rr[1] = ftanh(zW[nt][1]) + zL[nt][1] + bias.y;
                rr[2] = ftanh(zW[nt][2]) + zL[nt][2] + bias.z;
                rr[3] = ftanh(zW[nt][3]) + zL[nt][3] + bias.w;
                *(f32x4*)(op + nt * 16) = rr;
            }
        }
    }
}

extern "C" void kernel_launch(void* const* d_in, const int* in_sizes, int n_in,
                              void* d_out, int out_size, void* d_ws, size_t ws_size,
                              hipStream_t stream) {
    const int* ij = (const int*)d_in[0];
    const float* desc = (const float*)d_in[1];
    const float* layer1 = (const float*)d_in[2];
    const float* lin_w = (const float*)d_in[3];
    const float* lin_b = (const float*)d_in[4];
    float* out = (float*)d_out;
    const int E = in_sizes[0];

    k_fused<<<NBLK, 512, 0, stream>>>(ij, desc, layer1, lin_w, lin_b, out, E, 4);
}

// Round 19
// 40.583 us; speedup vs baseline: 1.3599x; 1.3599x over previous
//
#include <hip/hip_runtime.h>
#include <hip/hip_bf16.h>

typedef __attribute__((ext_vector_type(8))) short bf16x8;
typedef __attribute__((ext_vector_type(4))) float f32x4;

#define NBLK 256   // k_main blocks; 1024 threads (16 waves); 1 block/CU (96 KB LDS), 4 waves/SIMD

__device__ __forceinline__ unsigned short f2bf(float f) {
    unsigned u = __float_as_uint(f);
    return (unsigned short)((u + 0x7fffu + ((u >> 16) & 1u)) >> 16);
}

__device__ __forceinline__ bf16x8 pack8(float4 x, float4 y) {
    bf16x8 r;
    r[0] = (short)f2bf(x.x); r[1] = (short)f2bf(x.y);
    r[2] = (short)f2bf(x.z); r[3] = (short)f2bf(x.w);
    r[4] = (short)f2bf(y.x); r[5] = (short)f2bf(y.y);
    r[6] = (short)f2bf(y.z); r[7] = (short)f2bf(y.w);
    return r;
}

__device__ __forceinline__ float ftanh(float x) {
    float e = __expf(2.f * x);
    return 1.f - 2.f / (e + 1.f);
}

// ---- tiny pre-pack: 11 matrices -> bf16 A-fragment layout in ws (~88 KB) ----
__global__ void k_pack(const float* __restrict__ layer1, const float* __restrict__ lin_w,
                       __hip_bfloat16* __restrict__ wpk) {
    const int m = blockIdx.x;                 // 0..10 (10 = lin_w)
    const float* src = (m < 10) ? (layer1 + m * 4096) : lin_w;
    __hip_bfloat16* dst = wpk + m * 4096;
    for (int idx = threadIdx.x; idx < 512; idx += 256) {
        const int fi = idx >> 6, l = idx & 63;
        const int nt = fi >> 1, kk = fi & 1;
        const float* sp = src + (nt * 16 + (l & 15)) * 64 + kk * 32 + (l >> 4) * 8;
        float4 x = *(const float4*)sp;
        float4 y = *(const float4*)(sp + 4);
        *(bf16x8*)(dst + idx * 8) = pack8(x, y);
    }
}

// ---- main: sorted masked-fused, async-staged weights, wave-pair windows ----
// R18 probe: steady 13us = latency/MLP-limited (VALU 41%, MFMA 11%, no pipe
// saturated, HBM 3.3/6.3 TB/s); "startup" 10us = cold desc (~5, mandatory) +
// staging/ramp (~5, attacked here). Changes: (1) weights pre-packed in ws ->
// k_main stages 96KB via global_load_lds width-16 (6 async insts/thread, no
// cvt VALU, half the bytes); ij issued BEFORE the staging stream; (2) 1024-thr
// blocks -> 4 waves/SIMD (2x latency hiding); wave-pairs share a 64-edge
// window (redundant ballot sort, disjoint 2-tile halves).
// Layout (verified R1-R5): A row=lane&15, k=(lane>>4)*8+j; B col=lane&15
// (edge), same k; D col=lane&15 (edge), row=(lane>>4)*4+r -> f32x4 store/nt.
__global__ __launch_bounds__(1024, 4) void k_main(
    const int* __restrict__ ij, const float* __restrict__ desc,
    const __hip_bfloat16* __restrict__ wpk, const float* __restrict__ lin_b,
    float* __restrict__ out, int E) {

    __shared__ __align__(16) short wsm[12 * 4096];   // 96 KiB (11 used + pad)

    const int tid = threadIdx.x;
    const int lane = tid & 63;
    const int wid = tid >> 6;
    const int col = lane & 15;
    const int g = lane >> 4;
    const int kb = g * 8;
    const bf16x8 zero8 = {0, 0, 0, 0, 0, 0, 0, 0};

    const int gwave = blockIdx.x * 16 + wid;
    const int win = gwave >> 1;                    // wave-pair shares a window
    const int base = win * 64;
    const bool active = base < E;

    // ---- issue ij load FIRST (oldest in vmcnt FIFO -> its wait won't drain staging) ----
    int ty_own = 0, e_own = 0;
    if (active) {
        e_own = min(base + lane, E - 1);
        ty_own = ij[e_own];                         // in flight
    }

    // ---- async-stage 96 KB of pre-packed fragments (no VGPR round-trip) ----
    #pragma unroll
    for (int it = 0; it < 6; ++it) {
        const int off = it * 16384 + tid * 16;      // bytes
        __builtin_amdgcn_global_load_lds((const char*)wpk + off, (char*)wsm + off, 16, 0, 0);
    }

    // ---- sort the window while staging streams (needs only ty_own) ----
    int e_sorted = 0, ty_sorted = 0;
    if (active) {
        int rank = 0, below = 0;
        #pragma unroll
        for (int t = 0; t < 10; ++t) {
            const unsigned long long m = __ballot(ty_own == t);
            if (ty_own == t) rank = below + (int)__popcll(m & ((1ull << lane) - 1ull));
            below += (int)__popcll(m);
        }
        e_sorted = __builtin_amdgcn_ds_permute(rank << 2, e_own);
        ty_sorted = __builtin_amdgcn_ds_permute(rank << 2, ty_own);
    }

    // ---- my 2 tiles (disjoint half of the pair's 4) + desc loads in flight ----
    const int tp0 = (wid & 1) * 2;
    int e_t[2], ty_t[2], lo[2], hi[2];
    float4 dx0[2], dy0[2], dx1[2], dy1[2];
    if (active) {
        #pragma unroll
        for (int q = 0; q < 2; ++q) {
            const int pb = (tp0 + q) * 16;
            e_t[q] = __shfl(e_sorted, pb + col);
            ty_t[q] = __shfl(ty_sorted, pb + col);
            lo[q] = __shfl(ty_sorted, pb);
            hi[q] = __shfl(ty_sorted, pb + 15);
            const float* dp = desc + (size_t)e_t[q] * 64 + kb;
            dx0[q] = *(const float4*)dp;        dy0[q] = *(const float4*)(dp + 4);
            dx1[q] = *(const float4*)(dp + 32); dy1[q] = *(const float4*)(dp + 36);
        }
    }

    __syncthreads();   // drains staging + all loads

    if (!active) return;

    // lin fragments resident in registers (m=10 staged frags)
    bf16x8 al[4][2];
    #pragma unroll
    for (int fi = 0; fi < 8; ++fi)
        al[fi >> 1][fi & 1] = *(const bf16x8*)(&wsm[((80 + fi) * 64 + lane) * 8]);

    #pragma unroll 1
    for (int q = 0; q < 2; ++q) {
        const bf16x8 b0 = pack8(dx0[q], dy0[q]);
        const bf16x8 b1 = pack8(dx1[q], dy1[q]);
        const int tyq = ty_t[q];

        f32x4 zL[4], zW[4];
        #pragma unroll
        for (int nt = 0; nt < 4; ++nt) {
            f32x4 z = {0.f, 0.f, 0.f, 0.f};
            z = __builtin_amdgcn_mfma_f32_16x16x32_bf16(al[nt][0], b0, z, 0, 0, 0);
            zL[nt] = __builtin_amdgcn_mfma_f32_16x16x32_bf16(al[nt][1], b1, z, 0, 0, 0);
            zW[nt] = (f32x4){0.f, 0.f, 0.f, 0.f};
        }

        #pragma unroll 1
        for (int m = lo[q]; m <= hi[q]; ++m) {
            if (!__any(tyq == m)) continue;
            const bf16x8 m0 = (tyq == m) ? b0 : zero8;
            const bf16x8 m1 = (tyq == m) ? b1 : zero8;
            #pragma unroll
            for (int nt = 0; nt < 4; ++nt) {
                const bf16x8 f0 = *(const bf16x8*)(&wsm[((m * 8 + nt * 2 + 0) * 64 + lane) * 8]);
                const bf16x8 f1 = *(const bf16x8*)(&wsm[((m * 8 + nt * 2 + 1) * 64 + lane) * 8]);
                zW[nt] = __builtin_amdgcn_mfma_f32_16x16x32_bf16(f0, m0, zW[nt], 0, 0, 0);
                zW[nt] = __builtin_amdgcn_mfma_f32_16x16x32_bf16(f1, m1, zW[nt], 0, 0, 0);
            }
        }

        float* op = out + (size_t)e_t[q] * 64 + g * 4;
        #pragma unroll
        for (int nt = 0; nt < 4; ++nt) {
            const float4 bias = *(const float4*)(lin_b + nt * 16 + g * 4);
            f32x4 r;
            r[0] = ftanh(zW[nt][0]) + zL[nt][0] + bias.x;
            r[1] = ftanh(zW[nt][1]) + zL[nt][1] + bias.y;
            r[2] = ftanh(zW[nt][2]) + zL[nt][2] + bias.z;
            r[3] = ftanh(zW[nt][3]) + zL[nt][3] + bias.w;
            *(f32x4*)(op + nt * 16) = r;
        }
    }
}

// ---------------- fallback (ws too small): wave-per-edge fp32 ----------------
__global__ void k_naive(const int* __restrict__ ij, const float* __restrict__ desc,
                        const float* __restrict__ layer1, const float* __restrict__ lin_w,
                        const float* __restrict__ lin_b, float* __restrict__ out, int E) {
    const int wid = (blockIdx.x * blockDim.x + threadIdx.x) >> 6;
    const int lane = threadIdx.x & 63;
    const int nw = (gridDim.x * blockDim.x) >> 6;
    for (int e = wid; e < E; e += nw) {
        const int t = ij[e];
        const float d = desc[(size_t)e * 64 + lane];
        const float* Wr = layer1 + t * 4096 + lane * 64;
        const float* Lr = lin_w + lane * 64;
        float a1 = 0.f, a2 = 0.f;
        #pragma unroll
        for (int i = 0; i < 64; i += 4) {
            float4 w4 = *(const float4*)(Wr + i);
            float4 l4 = *(const float4*)(Lr + i);
            const float d0 = __shfl(d, i), d1 = __shfl(d, i + 1);
            const float d2 = __shfl(d, i + 2), d3 = __shfl(d, i + 3);
            a1 = fmaf(w4.x, d0, fmaf(w4.y, d1, fmaf(w4.z, d2, fmaf(w4.w, d3, a1))));
            a2 = fmaf(l4.x, d0, fmaf(l4.y, d1, fmaf(l4.z, d2, fmaf(l4.w, d3, a2))));
        }
        out[(size_t)e * 64 + lane] = tanhf(a1) + a2 + lin_b[lane];
    }
}

extern "C" void kernel_launch(void* const* d_in, const int* in_sizes, int n_in,
                              void* d_out, int out_size, void* d_ws, size_t ws_size,
                              hipStream_t stream) {
    const int* ij = (const int*)d_in[0];
    const float* desc = (const float*)d_in[1];
    const float* layer1 = (const float*)d_in[2];
    const float* lin_w = (const float*)d_in[3];
    const float* lin_b = (const float*)d_in[4];
    float* out = (float*)d_out;
    const int E = in_sizes[0];

    const size_t need = (size_t)12 * 4096 * sizeof(__hip_bfloat16) + 64;
    if (ws_size < need) {
        k_naive<<<2048, 256, 0, stream>>>(ij, desc, layer1, lin_w, lin_b, out, E);
        return;
    }
    __hip_bfloat16* wpk = (__hip_bfloat16*)d_ws;   // 12*4096 bf16 (11 used + pad)

    k_pack<<<11, 256, 0, stream>>>(layer1, lin_w, wpk);
    k_main<<<NBLK, 1024, 0, stream>>>(ij, desc, wpk, lin_b, out, E);
}

// Round 20
// 25.312 us; speedup vs baseline: 2.1803x; 1.6033x over previous
//
#include <hip/hip_runtime.h>
#include <hip/hip_bf16.h>

typedef __attribute__((ext_vector_type(8))) short bf16x8;
typedef __attribute__((ext_vector_type(4))) float f32x4;

#define NBLK 256   // blocks; 512 threads (8 waves); 1 block/CU (88 KB LDS), 2 waves/SIMD

__device__ __forceinline__ unsigned short f2bf(float f) {
    unsigned u = __float_as_uint(f);
    return (unsigned short)((u + 0x7fffu + ((u >> 16) & 1u)) >> 16);
}

__device__ __forceinline__ bf16x8 pack8(float4 x, float4 y) {
    bf16x8 r;
    r[0] = (short)f2bf(x.x); r[1] = (short)f2bf(x.y);
    r[2] = (short)f2bf(x.z); r[3] = (short)f2bf(x.w);
    r[4] = (short)f2bf(y.x); r[5] = (short)f2bf(y.y);
    r[6] = (short)f2bf(y.z); r[7] = (short)f2bf(y.w);
    return r;
}

__device__ __forceinline__ float ftanh(float x) {
    float e = __expf(2.f * x);
    return 1.f - 2.f / (e + 1.f);
}

// ---- tiny pre-pack: 11 matrices -> bf16 A-fragment layout in ws (~88 KB) ----
__global__ void k_pack(const float* __restrict__ layer1, const float* __restrict__ lin_w,
                       __hip_bfloat16* __restrict__ wpk) {
    const int m = blockIdx.x;                 // 0..10 (10 = lin_w)
    const float* src = (m < 10) ? (layer1 + m * 4096) : lin_w;
    __hip_bfloat16* dst = wpk + m * 4096;
    for (int idx = threadIdx.x; idx < 512; idx += 256) {
        const int fi = idx >> 6, l = idx & 63;
        const int nt = fi >> 1, kk = fi & 1;
        const float* sp = src + (nt * 16 + (l & 15)) * 64 + kk * 32 + (l >> 4) * 8;
        float4 x = *(const float4*)sp;
        float4 y = *(const float4*)(sp + 4);
        *(bf16x8*)(dst + idx * 8) = pack8(x, y);
    }
}

// ---- main: R16 structure (24.1us best) + cheap staging + range m-loop ----
// Changes vs R16, each small & separable (R19's bundled redesign regressed):
//  (1) weights pre-packed in ws -> staging = 11 bf16x8 loads + ds_writes per
//      thread, ZERO cvt VALU, half the global bytes; plain loads (no
//      global_load_lds, no load convoy -- R19 suspect);
//  (2) ij load + ballot sort hoisted above staging (cold miss drains under it);
//  (3) m-loop runs the contiguous [lo,hi] range without __any: a 16-slice of
//      a sorted 64-window contains every type in its range (runs contiguous;
//      whole-window-absent types ~1e-3/window) -> less SALU, better pipelining.
// NOTE (R13/R14): block-level LDS binning regressed 10x — do not revisit.
// Layout (verified R1-R5): A row=lane&15, k=(lane>>4)*8+j; B col=lane&15
// (edge), same k; D col=lane&15 (edge), row=(lane>>4)*4+r -> f32x4 store/nt.
__global__ __launch_bounds__(512, 2) void k_main(
    const int* __restrict__ ij, const float* __restrict__ desc,
    const __hip_bfloat16* __restrict__ wpk, const float* __restrict__ lin_b,
    float* __restrict__ out, int E) {

    __shared__ __align__(16) short wsm[11 * 512 * 8];   // 88 KiB; m=10 is lin_w

    const int lane = threadIdx.x & 63;
    const int col = lane & 15;
    const int g = lane >> 4;
    const int kb = g * 8;
    const bf16x8 zero8 = {0, 0, 0, 0, 0, 0, 0, 0};

    const int gw = blockIdx.x * 8 + (threadIdx.x >> 6);
    const int base = gw * 64;
    const bool active = base < E;

    // ---- phase 0: ij load + sort (cold ij miss overlaps staging below) ----
    int e_own = 0, ty_own = 0;
    if (active) {
        e_own = min(base + lane, E - 1);
        ty_own = ij[e_own];
    }

    // ---- stage 88 KB pre-packed fragments: 11 x (16B load + ds_write)/thread ----
    {
        const int t16 = threadIdx.x * 16;   // byte offset of this thread's first chunk
        #pragma unroll
        for (int it = 0; it < 11; ++it) {
            const int off = it * 8192 + t16;
            const bf16x8 v = *(const bf16x8*)((const char*)wpk + off);
            *(bf16x8*)((char*)wsm + off) = v;
        }
    }

    int e_sorted = 0, ty_sorted = 0;
    if (active) {
        int rank = 0, below = 0;
        #pragma unroll
        for (int t = 0; t < 10; ++t) {
            const unsigned long long m = __ballot(ty_own == t);
            if (ty_own == t) rank = below + (int)__popcll(m & ((1ull << lane) - 1ull));
            below += (int)__popcll(m);
        }
        e_sorted = __builtin_amdgcn_ds_permute(rank << 2, e_own);
        ty_sorted = __builtin_amdgcn_ds_permute(rank << 2, ty_own);
    }
    float4 bias[4];
    #pragma unroll
    for (int nt = 0; nt < 4; ++nt) bias[nt] = *(const float4*)(lin_b + nt * 16 + g * 4);

    __syncthreads();

    if (!active) return;

    // lin fragments resident in registers (m=10 staged frags)
    bf16x8 al[4][2];
    #pragma unroll
    for (int fi = 0; fi < 8; ++fi)
        al[fi >> 1][fi & 1] = *(const bf16x8*)(&wsm[((80 + fi) * 64 + lane) * 8]);

    // ---- 4 sorted 16-edge tiles ----
    #pragma unroll 1
    for (int tp = 0; tp < 4; ++tp) {
        const int pbase = tp * 16;
        const int e_t = __shfl(e_sorted, pbase + col);
        const int ty_t = __shfl(ty_sorted, pbase + col);
        const int ty_lo = __shfl(ty_sorted, pbase);
        const int ty_hi = __shfl(ty_sorted, pbase + 15);

        const float* dp = desc + (size_t)e_t * 64 + kb;
        const float4 x0 = *(const float4*)dp,        y0 = *(const float4*)(dp + 4);
        const float4 x1 = *(const float4*)(dp + 32), y1 = *(const float4*)(dp + 36);
        const bf16x8 b0 = pack8(x0, y0);
        const bf16x8 b1 = pack8(x1, y1);

        f32x4 zL[4], zW[4];
        #pragma unroll
        for (int nt = 0; nt < 4; ++nt) {
            f32x4 z = {0.f, 0.f, 0.f, 0.f};
            z = __builtin_amdgcn_mfma_f32_16x16x32_bf16(al[nt][0], b0, z, 0, 0, 0);
            zL[nt] = __builtin_amdgcn_mfma_f32_16x16x32_bf16(al[nt][1], b1, z, 0, 0, 0);
            zW[nt] = (f32x4){0.f, 0.f, 0.f, 0.f};
        }

        // W path over the tile's contiguous sorted type range (no __any: every
        // m in [lo,hi] is present up to ~1e-3/window whole-window absences)
        #pragma unroll 1
        for (int m = ty_lo; m <= ty_hi; ++m) {
            const bf16x8 m0 = (ty_t == m) ? b0 : zero8;
            const bf16x8 m1 = (ty_t == m) ? b1 : zero8;
            #pragma unroll
            for (int nt = 0; nt < 4; ++nt) {
                const bf16x8 f0 = *(const bf16x8*)(&wsm[((m * 8 + nt * 2 + 0) * 64 + lane) * 8]);
                const bf16x8 f1 = *(const bf16x8*)(&wsm[((m * 8 + nt * 2 + 1) * 64 + lane) * 8]);
                zW[nt] = __builtin_amdgcn_mfma_f32_16x16x32_bf16(f0, m0, zW[nt], 0, 0, 0);
                zW[nt] = __builtin_amdgcn_mfma_f32_16x16x32_bf16(f1, m1, zW[nt], 0, 0, 0);
            }
        }

        float* op = out + (size_t)e_t * 64 + g * 4;
        #pragma unroll
        for (int nt = 0; nt < 4; ++nt) {
            f32x4 r;
            r[0] = ftanh(zW[nt][0]) + zL[nt][0] + bias[nt].x;
            r[1] = ftanh(zW[nt][1]) + zL[nt][1] + bias[nt].y;
            r[2] = ftanh(zW[nt][2]) + zL[nt][2] + bias[nt].z;
            r[3] = ftanh(zW[nt][3]) + zL[nt][3] + bias[nt].w;
            *(f32x4*)(op + nt * 16) = r;
        }
    }
}

// ---------------- fallback (ws too small): wave-per-edge fp32 ----------------
__global__ void k_naive(const int* __restrict__ ij, const float* __restrict__ desc,
                        const float* __restrict__ layer1, const float* __restrict__ lin_w,
                        const float* __restrict__ lin_b, float* __restrict__ out, int E) {
    const int wid = (blockIdx.x * blockDim.x + threadIdx.x) >> 6;
    const int lane = threadIdx.x & 63;
    const int nw = (gridDim.x * blockDim.x) >> 6;
    for (int e = wid; e < E; e += nw) {
        const int t = ij[e];
        const float d = desc[(size_t)e * 64 + lane];
        const float* Wr = layer1 + t * 4096 + lane * 64;
        const float* Lr = lin_w + lane * 64;
        float a1 = 0.f, a2 = 0.f;
        #pragma unroll
        for (int i = 0; i < 64; i += 4) {
            float4 w4 = *(const float4*)(Wr + i);
            float4 l4 = *(const float4*)(Lr + i);
            const float d0 = __shfl(d, i), d1 = __shfl(d, i + 1);
            const float d2 = __shfl(d, i + 2), d3 = __shfl(d, i + 3);
            a1 = fmaf(w4.x, d0, fmaf(w4.y, d1, fmaf(w4.z, d2, fmaf(w4.w, d3, a1))));
            a2 = fmaf(l4.x, d0, fmaf(l4.y, d1, fmaf(l4.z, d2, fmaf(l4.w, d3, a2))));
        }
        out[(size_t)e * 64 + lane] = tanhf(a1) + a2 + lin_b[lane];
    }
}

extern "C" void kernel_launch(void* const* d_in, const int* in_sizes, int n_in,
                              void* d_out, int out_size, void* d_ws, size_t ws_size,
                              hipStream_t stream) {
    const int* ij = (const int*)d_in[0];
    const float* desc = (const float*)d_in[1];
    const float* layer1 = (const float*)d_in[2];
    const float* lin_w = (const float*)d_in[3];
    const float* lin_b = (const float*)d_in[4];
    float* out = (float*)d_out;
    const int E = in_sizes[0];

    const size_t need = (size_t)11 * 4096 * sizeof(__hip_bfloat16) + 64;
    if (ws_size < need) {
        k_naive<<<2048, 256, 0, stream>>>(ij, desc, layer1, lin_w, lin_b, out, E);
        return;
    }
    __hip_bfloat16* wpk = (__hip_bfloat16*)d_ws;   // 11*4096 bf16

    k_pack<<<11, 256, 0, stream>>>(layer1, lin_w, wpk);
    k_main<<<NBLK, 512, 0, stream>>>(ij, desc, wpk, lin_b, out, E);
}

// Round 21
// 24.256 us; speedup vs baseline: 2.2752x; 1.0435x over previous
//
#include <hip/hip_runtime.h>
#include <hip/hip_bf16.h>

typedef __attribute__((ext_vector_type(8))) short bf16x8;
typedef __attribute__((ext_vector_type(4))) float f32x4;

#define NBLK 256   // blocks; 512 threads (8 waves); 1 block/CU (88 KB LDS), 2 waves/SIMD

__device__ __forceinline__ unsigned short f2bf(float f) {
    unsigned u = __float_as_uint(f);
    return (unsigned short)((u + 0x7fffu + ((u >> 16) & 1u)) >> 16);
}

__device__ __forceinline__ bf16x8 pack8(float4 x, float4 y) {
    bf16x8 r;
    r[0] = (short)f2bf(x.x); r[1] = (short)f2bf(x.y);
    r[2] = (short)f2bf(x.z); r[3] = (short)f2bf(x.w);
    r[4] = (short)f2bf(y.x); r[5] = (short)f2bf(y.y);
    r[6] = (short)f2bf(y.z); r[7] = (short)f2bf(y.w);
    return r;
}

__device__ __forceinline__ float ftanh(float x) {
    float e = __expf(2.f * x);
    return 1.f - 2.f / (e + 1.f);
}

// FINAL: measured-best configuration (R16, 24.1us). Masked-fused single
// dispatch + in-wave ballot sort. Each wave owns a 64-edge window: stable
// ballot-rank by type, ds_permute to sorted lane order -> 4 sorted 16-edge
// tiles; E[distinct types/tile] ~3.1 (vs 8.1 unsorted) cuts m-iterations,
// frag ds_reads, MFMA and cndmask ~2.5x. Weights staged once to LDS (88 KB);
// lin frags in registers. Plateau evidence (R16-R20): reschedules, occupancy
// 2->4, staging diet via pre-pack (+1 dispatch), prefetch — all null-to-worse;
// steady state is latency-limited with no pipe >41% busy (R18 probe);
// remaining ~10us over the 10.5us HBM floor = cold-fetch serialization (~5)
// + launch/ramp (~4-5) + sort/epilogue VALU (~1).
// NOTE (R13/R14): block-level LDS binning regressed 10x — do not revisit.
// NOTE (R6/R7): nontemporal stores on 16B-interleaved output are benign, but
// scratch spill from live-set >128 VGPR causes symmetric FETCH/WRITE blowup.
// Layout (verified R1-R5): A row=lane&15, k=(lane>>4)*8+j; B col=lane&15
// (edge), same k; D col=lane&15 (edge), row=(lane>>4)*4+r -> f32x4 store/nt.
__global__ __launch_bounds__(512, 2) void k_fused(
    const int* __restrict__ ij, const float* __restrict__ desc,
    const float* __restrict__ layer1, const float* __restrict__ lin_w,
    const float* __restrict__ lin_b, float* __restrict__ out, int E) {

    __shared__ __align__(16) short wsm[11 * 512 * 8];   // 88 KiB; m=10 is lin_w

    for (int idx = threadIdx.x; idx < 11 * 512; idx += 512) {
        const int m = idx >> 9;
        const int fl = idx & 511;
        const int fi = fl >> 6, l = fl & 63;
        const int nt = fi >> 1, kk = fi & 1;
        const float* src = (m < 10) ? (layer1 + m * 4096) : lin_w;
        const float* sp = src + (nt * 16 + (l & 15)) * 64 + kk * 32 + (l >> 4) * 8;
        float4 x = *(const float4*)sp;
        float4 y = *(const float4*)(sp + 4);
        *(bf16x8*)(&wsm[idx * 8]) = pack8(x, y);
    }

    const int lane = threadIdx.x & 63;
    const int col = lane & 15;
    const int g = lane >> 4;
    const int kb = g * 8;
    const bf16x8 zero8 = {0, 0, 0, 0, 0, 0, 0, 0};

    __syncthreads();

    // lin fragments resident in registers (m=10 staged frags)
    bf16x8 al[4][2];
    #pragma unroll
    for (int fi = 0; fi < 8; ++fi)
        al[fi >> 1][fi & 1] = *(const bf16x8*)(&wsm[((80 + fi) * 64 + lane) * 8]);

    const int gw = blockIdx.x * 8 + (threadIdx.x >> 6);
    const int base = gw * 64;
    if (base >= E) return;

    // ---- in-wave sort of the 64-edge window by type (stable ballot rank) ----
    const int e_own = min(base + lane, E - 1);
    const int ty_own = ij[e_own];
    int rank = 0, below = 0;
    #pragma unroll
    for (int t = 0; t < 10; ++t) {
        const unsigned long long m = __ballot(ty_own == t);
        if (ty_own == t) rank = below + (int)__popcll(m & ((1ull << lane) - 1ull));
        below += (int)__popcll(m);
    }
    const int e_sorted = __builtin_amdgcn_ds_permute(rank << 2, e_own);
    const int ty_sorted = __builtin_amdgcn_ds_permute(rank << 2, ty_own);

    // ---- 4 sorted 16-edge tiles ----
    #pragma unroll 1
    for (int tp = 0; tp < 4; ++tp) {
        const int pbase = tp * 16;
        const int e_t = __shfl(e_sorted, pbase + col);
        const int ty_t = __shfl(ty_sorted, pbase + col);
        const int ty_lo = __shfl(ty_sorted, pbase);
        const int ty_hi = __shfl(ty_sorted, pbase + 15);

        const float* dp = desc + (size_t)e_t * 64 + kb;
        const float4 x0 = *(const float4*)dp,        y0 = *(const float4*)(dp + 4);
        const float4 x1 = *(const float4*)(dp + 32), y1 = *(const float4*)(dp + 36);
        const bf16x8 b0 = pack8(x0, y0);
        const bf16x8 b1 = pack8(x1, y1);

        // lin path + zero W accumulators
        f32x4 zL[4], zW[4];
        #pragma unroll
        for (int nt = 0; nt < 4; ++nt) {
            f32x4 z = {0.f, 0.f, 0.f, 0.f};
            z = __builtin_amdgcn_mfma_f32_16x16x32_bf16(al[nt][0], b0, z, 0, 0, 0);
            zL[nt] = __builtin_amdgcn_mfma_f32_16x16x32_bf16(al[nt][1], b1, z, 0, 0, 0);
            zW[nt] = (f32x4){0.f, 0.f, 0.f, 0.f};
        }

        // W path over the tile's (sorted, contiguous) type range
        #pragma unroll 1
        for (int m = ty_lo; m <= ty_hi; ++m) {
            if (!__any(ty_t == m)) continue;
            const bf16x8 m0 = (ty_t == m) ? b0 : zero8;
            const bf16x8 m1 = (ty_t == m) ? b1 : zero8;
            #pragma unroll
            for (int nt = 0; nt < 4; ++nt) {
                const bf16x8 f0 = *(const bf16x8*)(&wsm[((m * 8 + nt * 2 + 0) * 64 + lane) * 8]);
                const bf16x8 f1 = *(const bf16x8*)(&wsm[((m * 8 + nt * 2 + 1) * 64 + lane) * 8]);
                zW[nt] = __builtin_amdgcn_mfma_f32_16x16x32_bf16(f0, m0, zW[nt], 0, 0, 0);
                zW[nt] = __builtin_amdgcn_mfma_f32_16x16x32_bf16(f1, m1, zW[nt], 0, 0, 0);
            }
        }

        float* op = out + (size_t)e_t * 64 + g * 4;
        #pragma unroll
        for (int nt = 0; nt < 4; ++nt) {
            const float4 bias = *(const float4*)(lin_b + nt * 16 + g * 4);
            f32x4 r;
            r[0] = ftanh(zW[nt][0]) + zL[nt][0] + bias.x;
            r[1] = ftanh(zW[nt][1]) + zL[nt][1] + bias.y;
            r[2] = ftanh(zW[nt][2]) + zL[nt][2] + bias.z;
            r[3] = ftanh(zW[nt][3]) + zL[nt][3] + bias.w;
            *(f32x4*)(op + nt * 16) = r;
        }
    }
}

extern "C" void kernel_launch(void* const* d_in, const int* in_sizes, int n_in,
                              void* d_out, int out_size, void* d_ws, size_t ws_size,
                              hipStream_t stream) {
    const int* ij = (const int*)d_in[0];
    const float* desc = (const float*)d_in[1];
    const float* layer1 = (const float*)d_in[2];
    const float* lin_w = (const float*)d_in[3];
    const float* lin_b = (const float*)d_in[4];
    float* out = (float*)d_out;
    const int E = in_sizes[0];

    k_fused<<<NBLK, 512, 0, stream>>>(ij, desc, layer1, lin_w, lin_b, out, E);
}